// Round 1
// baseline (229.624 us; speedup 1.0000x reference)
//
#include <hip/hip_runtime.h>

// Sparsemax over last axis of (16, 2048, 1024) fp32.
// One wave (64 lanes) per row; 16 elements/lane held in registers.
// Michelot's simplex-projection algorithm replaces the reference's
// sort+cumsum: tau_{t+1} = (sum_{z>tau_t} z - 1) / |{z>tau_t}|,
// monotone, exact at fixed point (active-set cardinality stabilizes).

constexpr int N    = 1024;       // logits per row
constexpr int ROWS = 16 * 2048;  // B * S

__global__ __launch_bounds__(256) void sparsemax_kernel(const float* __restrict__ x,
                                                        float* __restrict__ out) {
    const int wid  = threadIdx.x >> 6;   // wave within block: 0..3
    const int lane = threadIdx.x & 63;
    const long long row = (long long)blockIdx.x * 4 + wid;

    const float4* xr   = reinterpret_cast<const float4*>(x   + row * (long long)N);
    float4*       outr = reinterpret_cast<float4*>      (out + row * (long long)N);

    // Load 16 floats/lane as 4 coalesced float4s (lane + 64*j).
    float z[16];
    #pragma unroll
    for (int j = 0; j < 4; ++j) {
        float4 v = xr[lane + 64 * j];
        z[4 * j + 0] = v.x; z[4 * j + 1] = v.y;
        z[4 * j + 2] = v.z; z[4 * j + 3] = v.w;
    }

    // Row max (stability shift; tau shifts identically so projection unchanged).
    float m = z[0];
    #pragma unroll
    for (int i = 1; i < 16; ++i) m = fmaxf(m, z[i]);
    #pragma unroll
    for (int o = 1; o < 64; o <<= 1) m = fmaxf(m, __shfl_xor(m, o, 64));

    // z -= max; full-row sum.
    float s = 0.f;
    #pragma unroll
    for (int i = 0; i < 16; ++i) { z[i] -= m; s += z[i]; }
    #pragma unroll
    for (int o = 1; o < 64; o <<= 1) s += __shfl_xor(s, o, 64);

    // Michelot iteration. Active set always contains the max element (z=0,
    // tau<0 invariant), so count >= 1; cardinality strictly decreases until
    // the fixed point, so the loop terminates in <= N iterations (~5 typ.).
    float tau  = (s - 1.0f) * (1.0f / (float)N);
    int kprev = N;
    for (int it = 0; it < N; ++it) {
        float ls = 0.f;
        int   lc = 0;
        #pragma unroll
        for (int i = 0; i < 16; ++i) {
            bool in = z[i] > tau;
            ls += in ? z[i] : 0.0f;
            lc += in ? 1 : 0;
        }
        #pragma unroll
        for (int o = 1; o < 64; o <<= 1) {
            ls += __shfl_xor(ls, o, 64);
            lc += __shfl_xor(lc, o, 64);
        }
        if (lc == kprev) break;   // active set stable -> tau is exact
        kprev = lc;
        tau = (ls - 1.0f) / (float)lc;
    }

    // out = max(z - tau, 0), coalesced float4 stores.
    #pragma unroll
    for (int j = 0; j < 4; ++j) {
        float4 o4;
        o4.x = fmaxf(z[4 * j + 0] - tau, 0.f);
        o4.y = fmaxf(z[4 * j + 1] - tau, 0.f);
        o4.z = fmaxf(z[4 * j + 2] - tau, 0.f);
        o4.w = fmaxf(z[4 * j + 3] - tau, 0.f);
        outr[lane + 64 * j] = o4;
    }
}

extern "C" void kernel_launch(void* const* d_in, const int* in_sizes, int n_in,
                              void* d_out, int out_size, void* d_ws, size_t ws_size,
                              hipStream_t stream) {
    const float* x   = (const float*)d_in[0];
    float*       out = (float*)d_out;
    dim3 grid(ROWS / 4), block(256);
    hipLaunchKernelGGL(sparsemax_kernel, grid, block, 0, stream, x, out);
}